// Round 3
// baseline (354.766 us; speedup 1.0000x reference)
//
#include <hip/hip_runtime.h>
#include <hip/hip_bf16.h>

// Packed varlen causal GQA attention (flash-style), MI355X gfx950.
// Q [T,H,D] f32, K/V [T,G,D] f32, cu_seqlens [9] int32 -> O [T,H,D] f32.
// T=4096, H=16, G=4, D=128, SCALE=1/sqrt(128).
//
// R11 = R10 with ONE change: chunk index moved from blockIdx.z (slowest
// dispatch dim) into the LOW BITS of blockIdx.x (fastest). R10's z-major
// order dispatched all cz=0 blocks first (one full machine round of 512
// slots), so a long tile's 4 chunks ran in sequential rounds -> critical
// path stayed ~64 iterations (124 us ~ 64 x 2us/iter; Occupancy 14%).
// With cz fastest and big-tiles-first, the longest tile's 4 chunks start
// concurrently at t=0: per-block chain <= 16 iters, total live work
// ~3800 block-iters over 512 slots ~ 7.4 rounds.
//
// Structure: cross-block split-K (flash-decoding). Grid (512,4):
// bx -> (qtile = 127-(bx>>2), cz = bx&3); 1024-key chunks; dead chunks
// exit immediately. Multi-chunk tiles write unnormalized (m,l,O) f32
// partials to workspace; attn_merge combines. Single-chunk tiles
// (majority) write O directly. Defer-rescale: skip the oacc*=alpha pass
// when no lane's running max grew (wave-uniform __any; alpha==1, exact).
// Fallback: if ws_size < 136.3 MB, launch the monolithic path.
//
// Per block: 512 threads = 8 waves: waves 0-3 (split 0) handle heads
// g*4+0..3 over the first half of the chunk's key range; waves 4-7
// (split 1) same heads over the second half. Independent (m,l,O) per
// split, merged through LDS at the end (merged max committed back into
// m_run -- R10 fix -- so the stored partial (m,l,O) share one reference).
// MFMA layouts (HW-verified m89/m91/m118-m122), 16x16x32_bf16:
//   A[m=lane&15][k=quad*8+j], B[k=quad*8+j][n=lane&15],
//   C/D: row m = quad*4+reg, col n = lane&15.

#define T_TOK 4096
#define NH    16
#define NG    4
#define HD    128
#define NCU   9

// Workspace layout (floats):
//   O_part[tile(128)][g(4)][chunk(4)][hw(4)][q(32)][d(128)]  = 33,554,432 f
//   ml    [tile][g][chunk][hw][q][{m,l}]                     =    524,288 f
#define ML_OFF 33554432l

typedef short          short8_t __attribute__((ext_vector_type(8)));
typedef float          float4_t __attribute__((ext_vector_type(4)));
typedef unsigned int   uint2_t  __attribute__((ext_vector_type(2)));
typedef unsigned short ushort;

static __device__ inline unsigned pack2(float a, float b) {
    __hip_bfloat162 h = __float22bfloat162_rn(make_float2(a, b));
    union { __hip_bfloat162 h; unsigned u; } c; c.h = h;
    return c.u;
}
static __device__ inline short8_t cvt8(float4_t lo, float4_t hi) {
    union { unsigned u[4]; short8_t s; } r;
    r.u[0] = pack2(lo[0], lo[1]); r.u[1] = pack2(lo[2], lo[3]);
    r.u[2] = pack2(hi[0], hi[1]); r.u[3] = pack2(hi[2], hi[3]);
    return r.s;
}

template <bool CHUNKED>
__global__ __launch_bounds__(512) void attn_fwd_k(
    const float* __restrict__ Q,
    const float* __restrict__ K,
    const float* __restrict__ V,
    const int*   __restrict__ cu,
    float*       __restrict__ O,
    float*       __restrict__ WS)
{
    // Carved shared memory (explicit offsets; combine phase reuses it):
    //   Ks[2][32][136] ushort : 17408 B  @ 0
    //   Vt[2][128][40] ushort : 20480 B  @ 17408
    //   pb[8][2][16][40]ushort: 20480 B  @ 37888   (total 58368 B)
    __shared__ __align__(16) unsigned char smem[58368];
    ushort (*Ks)[32][136]   = (ushort (*)[32][136])smem;
    ushort (*Vt)[128][40]   = (ushort (*)[128][40])(smem + 17408);
    ushort (*pb)[2][16][40] = (ushort (*)[2][16][40])(smem + 37888);

    // R11: chunk fastest, big tiles first (tile-descending, chunks adjacent)
    const int bx    = (int)blockIdx.x;
    const int cz    = CHUNKED ? (bx & 3) : 0;
    const int qtile = CHUNKED ? ((int)(gridDim.x >> 2) - 1 - (bx >> 2))
                              : ((int)gridDim.x - 1 - bx);
    const int g     = blockIdx.y;
    const int tid   = threadIdx.x;
    const int wave  = tid >> 6;          // 0..7
    const int split = wave >> 2;         // 0..1 (key-range half)
    const int hw    = wave & 3;
    const int lane  = tid & 63;
    const int h     = g * 4 + hw;        // query head; h//4 == g (jnp.repeat)
    const int col   = lane & 15;
    const int quad  = lane >> 4;

    const int qbase = qtile * 32;        // 32 q rows per block
    const int qq[2] = { qbase + col, qbase + 16 + col };

    // segment starts: per-lane per-tile, and block-uniform for k0
    int seg_start[2] = {0, 0}, seg0 = 0;
    #pragma unroll
    for (int j = 1; j < NCU; ++j) {
        int cj = cu[j];
        if (cj <= qq[0])  seg_start[0] = cj;
        if (cj <= qq[1])  seg_start[1] = cj;
        if (cj <= qbase)  seg0         = cj;
    }
    const int k0       = seg0 & ~31;
    const int nblk_tot = (qbase + 32 - k0) >> 5;      // 32-key blocks in span
    const int nc       = CHUNKED ? ((nblk_tot + 31) >> 5) : 1;
    if (CHUNKED && cz >= nc) return;                  // dead chunk (uniform)
    int nblk = nblk_tot - (cz << 5);                  // k-blocks in this chunk
    if (CHUNKED && nblk > 32) nblk = 32;              // non-last chunks: even
    const int nb0    = (nblk + 1) >> 1;               // iterations per split
    const int kstart = k0 + (cz << 10) + split * nb0 * 32;

    // Q fragments (B-operand of S^T = K*Q^T), 2 tiles. dim = c*32+quad*8+j.
    short8_t qf[2][4];
    #pragma unroll
    for (int tt = 0; tt < 2; ++tt) {
        const float* qp = Q + ((long)qq[tt] * NH + h) * HD + quad * 8;
        #pragma unroll
        for (int c = 0; c < 4; ++c)
            qf[tt][c] = cvt8(*(const float4_t*)(qp + c * 32),
                             *(const float4_t*)(qp + c * 32 + 4));
    }

    float4_t oacc[2][8];
    #pragma unroll
    for (int tt = 0; tt < 2; ++tt)
        #pragma unroll
        for (int dt = 0; dt < 8; ++dt) oacc[tt][dt] = (float4_t){0.f, 0.f, 0.f, 0.f};

    float m_run[2] = {-10000.0f, -10000.0f};
    float l_run[2] = {0.0f, 0.0f};
    const float c_scale = 0.08838834764831845f * 1.4426950408889634f; // SCALE*log2e

    // staging thread mapping (256 threads per split, 32 keys x 128 dims)
    const int stid = tid & 255;
    const int ki  = stid >> 3;           // K: key-in-tile
    const int ch  = (stid & 7) * 16;     // K: dim chunk
    const int kp2 = (stid & 15) * 2;     // V: key pair
    const int dc  = (stid >> 4) * 8;     // V: dim chunk

    float4_t kreg[4], vreg[4];
    {
        int key = kstart + ki; if (key > T_TOK - 1) key = T_TOK - 1;
        const float* kp = K + ((long)key * NG + g) * HD + ch;
        kreg[0] = *(const float4_t*)kp;       kreg[1] = *(const float4_t*)(kp + 4);
        kreg[2] = *(const float4_t*)(kp + 8); kreg[3] = *(const float4_t*)(kp + 12);
        int key0 = kstart + kp2;     if (key0 > T_TOK - 1) key0 = T_TOK - 1;
        int key1 = kstart + kp2 + 1; if (key1 > T_TOK - 1) key1 = T_TOK - 1;
        const float* v0 = V + ((long)key0 * NG + g) * HD + dc;
        const float* v1 = V + ((long)key1 * NG + g) * HD + dc;
        vreg[0] = *(const float4_t*)v0; vreg[1] = *(const float4_t*)(v0 + 4);
        vreg[2] = *(const float4_t*)v1; vreg[3] = *(const float4_t*)(v1 + 4);
    }

    for (int it = 0; it < nb0; ++it) {
        const int kb = kstart + it * 32;
        __syncthreads();   // previous iter's LDS reads complete

        // ---- write prefetched K/V regs -> LDS (bf16), own split's buffers ----
        *(short8_t*)&Ks[split][ki][ch]     = cvt8(kreg[0], kreg[1]);
        *(short8_t*)&Ks[split][ki][ch + 8] = cvt8(kreg[2], kreg[3]);
        #pragma unroll
        for (int d = 0; d < 4; ++d) {
            *(unsigned*)&Vt[split][dc + d][kp2]     = pack2(vreg[0][d], vreg[2][d]);
            *(unsigned*)&Vt[split][dc + 4 + d][kp2] = pack2(vreg[1][d], vreg[3][d]);
        }
        __syncthreads();

        // ---- prefetch next 32-key block (in flight during compute) ----
        {
            int nb = kb + 32;
            int key = nb + ki; if (key > T_TOK - 1) key = T_TOK - 1;
            const float* kp = K + ((long)key * NG + g) * HD + ch;
            kreg[0] = *(const float4_t*)kp;       kreg[1] = *(const float4_t*)(kp + 4);
            kreg[2] = *(const float4_t*)(kp + 8); kreg[3] = *(const float4_t*)(kp + 12);
            int key0 = nb + kp2;     if (key0 > T_TOK - 1) key0 = T_TOK - 1;
            int key1 = nb + kp2 + 1; if (key1 > T_TOK - 1) key1 = T_TOK - 1;
            const float* v0 = V + ((long)key0 * NG + g) * HD + dc;
            const float* v1 = V + ((long)key1 * NG + g) * HD + dc;
            vreg[0] = *(const float4_t*)v0; vreg[1] = *(const float4_t*)(v0 + 4);
            vreg[2] = *(const float4_t*)v1; vreg[3] = *(const float4_t*)(v1 + 4);
        }

        // ---- S^T tiles: 8 K-frag reads feed 16 MFMAs (2 q-tiles) ----
        float4_t st[2][2];
        #pragma unroll
        for (int tt = 0; tt < 2; ++tt)
            #pragma unroll
            for (int t = 0; t < 2; ++t) st[tt][t] = (float4_t){0.f, 0.f, 0.f, 0.f};
        #pragma unroll
        for (int c = 0; c < 4; ++c) {
            short8_t kf0 = *(const short8_t*)&Ks[split][col][c * 32 + quad * 8];
            short8_t kf1 = *(const short8_t*)&Ks[split][16 + col][c * 32 + quad * 8];
            st[0][0] = __builtin_amdgcn_mfma_f32_16x16x32_bf16(kf0, qf[0][c], st[0][0], 0, 0, 0);
            st[0][1] = __builtin_amdgcn_mfma_f32_16x16x32_bf16(kf1, qf[0][c], st[0][1], 0, 0, 0);
            st[1][0] = __builtin_amdgcn_mfma_f32_16x16x32_bf16(kf0, qf[1][c], st[1][0], 0, 0, 0);
            st[1][1] = __builtin_amdgcn_mfma_f32_16x16x32_bf16(kf1, qf[1][c], st[1][1], 0, 0, 0);
        }

        // ---- mask + online softmax per q-tile (log2 domain) ----
        #pragma unroll
        for (int tt = 0; tt < 2; ++tt) {
            float tv[8];
            #pragma unroll
            for (int t = 0; t < 2; ++t)
                #pragma unroll
                for (int r = 0; r < 4; ++r) {
                    int key = kb + 16 * t + quad * 4 + r;
                    bool valid = (key <= qq[tt]) && (key >= seg_start[tt]);
                    tv[t * 4 + r] = valid ? st[tt][t][r] * c_scale : -30000.0f;
                }
            float tmax = tv[0];
            #pragma unroll
            for (int i = 1; i < 8; ++i) tmax = fmaxf(tmax, tv[i]);
            tmax = fmaxf(tmax, __shfl_xor(tmax, 16));
            tmax = fmaxf(tmax, __shfl_xor(tmax, 32));
            const float m_new = fmaxf(m_run[tt], tmax);
            float p[8], ps = 0.f;
            #pragma unroll
            for (int i = 0; i < 8; ++i) { p[i] = __builtin_exp2f(tv[i] - m_new); ps += p[i]; }
            ps += __shfl_xor(ps, 16);
            ps += __shfl_xor(ps, 32);
            // defer-rescale: when no lane's max grew, alpha==1 exactly ->
            // skip the O rescale pass and m/l update (wave-uniform branch).
            if (__any(tmax > m_run[tt])) {
                const float alpha = __builtin_exp2f(m_run[tt] - m_new);
                l_run[tt] = l_run[tt] * alpha + ps;
                m_run[tt] = m_new;
                #pragma unroll
                for (int dt = 0; dt < 8; ++dt) oacc[tt][dt] *= alpha;
            } else {
                l_run[tt] += ps;
            }

            uint2_t w0; w0.x = pack2(p[0], p[1]); w0.y = pack2(p[2], p[3]);
            uint2_t w1; w1.x = pack2(p[4], p[5]); w1.y = pack2(p[6], p[7]);
            *(uint2_t*)&pb[wave][tt][col][quad * 4]      = w0;
            *(uint2_t*)&pb[wave][tt][col][16 + quad * 4] = w1;
        }
        short8_t pf0 = *(const short8_t*)&pb[wave][0][col][quad * 8];
        short8_t pf1 = *(const short8_t*)&pb[wave][1][col][quad * 8];

        // ---- O^T += V^T * P^T : 8 V-frag reads feed 16 MFMAs ----
        #pragma unroll
        for (int dt = 0; dt < 8; ++dt) {
            short8_t vf = *(const short8_t*)&Vt[split][dt * 16 + col][quad * 8];
            oacc[0][dt] = __builtin_amdgcn_mfma_f32_16x16x32_bf16(vf, pf0, oacc[0][dt], 0, 0, 0);
            oacc[1][dt] = __builtin_amdgcn_mfma_f32_16x16x32_bf16(vf, pf1, oacc[1][dt], 0, 0, 0);
        }
    }

    // ---- merge split1's (m,l,O) into split0 via LDS (region reuse) ----
    float* Ob = (float*)smem;                  // [4 heads][16 q][132] floats
    float* cm = (float*)(smem + 34816);        // 64 floats per pass
    float* cl = (float*)(smem + 35840);
    #pragma unroll
    for (int tt = 0; tt < 2; ++tt) {
        __syncthreads();
        if (split == 1) {
            if (quad == 0) { cm[hw * 16 + col] = m_run[tt]; cl[hw * 16 + col] = l_run[tt]; }
            float* ob = Ob + (hw * 16 + col) * 132;
            #pragma unroll
            for (int dt = 0; dt < 8; ++dt)
                *(float4_t*)(ob + dt * 16 + quad * 4) = oacc[tt][dt];
        }
        __syncthreads();
        if (split == 0) {
            const float m1 = cm[hw * 16 + col], l1 = cl[hw * 16 + col];
            const float m  = fmaxf(m_run[tt], m1);
            const float a0 = __builtin_exp2f(m_run[tt] - m);
            const float a1 = __builtin_exp2f(m1 - m);
            const float* ob = Ob + (hw * 16 + col) * 132;
            #pragma unroll
            for (int dt = 0; dt < 8; ++dt) {
                float4_t o1 = *(const float4_t*)(ob + dt * 16 + quad * 4);
                oacc[tt][dt] = oacc[tt][dt] * a0 + o1 * a1;
            }
            l_run[tt] = l_run[tt] * a0 + l1 * a1;
            m_run[tt] = m;   // commit merged max: partial path stores (m,l,O)
                             // and all three must share one reference max
        }
    }

    // ---- epilogue (split 0 only) ----
    if (split == 0) {
        if (!CHUNKED || nc == 1) {
            // whole span in this block: normalized direct store
            #pragma unroll
            for (int tt = 0; tt < 2; ++tt) {
                const float inv_l = 1.0f / l_run[tt];
                float* op = O + ((long)qq[tt] * NH + h) * HD + quad * 4;
                #pragma unroll
                for (int dt = 0; dt < 8; ++dt) {
                    float4_t ov;
                    #pragma unroll
                    for (int r = 0; r < 4; ++r) ov[r] = oacc[tt][dt][r] * inv_l;
                    *(float4_t*)(op + dt * 16) = ov;
                }
            }
        } else {
            // multi-chunk: write unnormalized partial (m,l,O) to workspace
            const long slot = ((long)(qtile * 4 + g)) * 4 + cz;
            #pragma unroll
            for (int tt = 0; tt < 2; ++tt) {
                const int ql = tt * 16 + col;
                if (quad == 0) {
                    float* mlp = WS + ML_OFF + (slot * 128 + hw * 32 + ql) * 2;
                    mlp[0] = m_run[tt];
                    mlp[1] = l_run[tt];
                }
                float* op = WS + (slot * 128 + hw * 32 + ql) * 128 + quad * 4;
                #pragma unroll
                for (int dt = 0; dt < 8; ++dt)
                    *(float4_t*)(op + dt * 16) = oacc[tt][dt];
            }
        }
    }
}

// Combine up to 4 chunk partials per (tile, g). Online merge, f32, log2
// domain. Only runs for multi-chunk tiles (the partial kernel already
// wrote O directly for nc==1).
__global__ __launch_bounds__(256) void attn_merge(
    const int*   __restrict__ cu,
    const float* __restrict__ WS,
    float*       __restrict__ O)
{
    const int tile  = blockIdx.x;
    const int g     = blockIdx.y;
    const int qbase = tile * 32;
    int seg0 = 0;
    #pragma unroll
    for (int j = 1; j < NCU; ++j) { int cj = cu[j]; if (cj <= qbase) seg0 = cj; }
    const int k0       = seg0 & ~31;
    const int nblk_tot = (qbase + 32 - k0) >> 5;
    const int nc       = (nblk_tot + 31) >> 5;
    if (nc <= 1) return;

    const int tid  = threadIdx.x;
    const int pair = tid >> 1;           // hw*32 + q  (128 pairs)
    const int half = tid & 1;            // which 64-float half of D
    const int hw   = pair >> 5;
    const int q    = pair & 31;

    float m = -30000.0f, l = 0.0f;
    float4_t acc[16];
    #pragma unroll
    for (int i = 0; i < 16; ++i) acc[i] = (float4_t){0.f, 0.f, 0.f, 0.f};

    for (int c = 0; c < nc; ++c) {
        const long slot = ((long)(tile * 4 + g)) * 4 + c;
        const float* mlp = WS + ML_OFF + (slot * 128 + pair) * 2;
        const float mc = mlp[0], lc = mlp[1];
        const float mn = fmaxf(m, mc);
        const float a0 = __builtin_exp2f(m - mn);   // empty chunk: mc=-1e4, w->0
        const float a1 = __builtin_exp2f(mc - mn);
        l = l * a0 + lc * a1;
        const float* op = WS + (slot * 128 + pair) * 128 + half * 64;
        #pragma unroll
        for (int i = 0; i < 16; ++i) {
            float4_t v = *(const float4_t*)(op + i * 4);
            acc[i] = acc[i] * a0 + v * a1;
        }
        m = mn;
    }
    const float inv = 1.0f / l;
    float* o = O + ((long)(qbase + q) * NH + g * 4 + hw) * HD + half * 64;
    #pragma unroll
    for (int i = 0; i < 16; ++i)
        *(float4_t*)(o + i * 4) = acc[i] * inv;
}

extern "C" void kernel_launch(void* const* d_in, const int* in_sizes, int n_in,
                              void* d_out, int out_size, void* d_ws, size_t ws_size,
                              hipStream_t stream) {
    const float* Q  = (const float*)d_in[0];
    const float* K  = (const float*)d_in[1];
    const float* V  = (const float*)d_in[2];
    const int*   cu = (const int*)d_in[3];
    float*       O  = (float*)d_out;
    const size_t need = (size_t)(33554432l + 524288l) * sizeof(float); // 136.3 MB
    if (d_ws != nullptr && ws_size >= need) {
        // x = (tile,chunk) with chunk fastest; tiles descending (big first)
        attn_fwd_k<true><<<dim3((T_TOK / 32) * 4, NG), 512, 0, stream>>>(
            Q, K, V, cu, O, (float*)d_ws);
        attn_merge<<<dim3(T_TOK / 32, NG), 256, 0, stream>>>(
            cu, (const float*)d_ws, O);
    } else {
        // workspace too small: proven monolithic path (R8 behavior)
        attn_fwd_k<false><<<dim3(T_TOK / 32, NG), 512, 0, stream>>>(
            Q, K, V, cu, O, nullptr);
    }
}

// Round 4
// 188.237 us; speedup vs baseline: 1.8847x; 1.8847x over previous
//
#include <hip/hip_runtime.h>
#include <hip/hip_bf16.h>

// Packed varlen causal GQA attention (flash-style), MI355X gfx950.
// Q [T,H,D] f32, K/V [T,G,D] f32, cu_seqlens [9] int32 -> O [T,H,D] f32.
// T=4096, H=16, G=4, D=128, SCALE=1/sqrt(128).
//
// R12 = R10's verified tile body, driven by a PERSISTENT work queue.
// History: R10 (split-K, z-major grid) = 124 us, Occ 14% -- 3/4 of
// dispatched blocks were dead chunks and live work ran in sparse rounds.
// R11 (chunk-fastest in x) = 272 us, Occ 5.8% -- the first 512 dispatched
// blocks were all g=0 (y slow), so live density fell to ~1/4 per round
// and tau_iter inflated (prefetch latency exposed at ~5 waves/CU).
// Block-residency was conserved across both (~17k block-us): the limiter
// is LIVE-BLOCK DENSITY, i.e. a compaction problem, not an order problem.
//
// Fix: build_queue (1 block) emits a compacted list of only the live
// (tile, g, chunk) items, heaviest tiles first, and resets a pop counter
// (re-runs every launch -> replay/graph safe). attn_fwd_persist launches
// exactly 512 blocks (2/CU, fully resident), each atomically popping
// items and running the unchanged R10 body. Zero dead blocks; heavy
// 16-iter chains start at t=0; refill via atomic pop.
//
// Per item: 512 threads = 8 waves; waves 0-3 (split 0) handle heads
// g*4+0..3 over the first half of the chunk's key range; waves 4-7
// (split 1) the second half. Independent (m,l,O) per split, merged via
// LDS; merged max committed back into m_run (R10 fix) so stored partials
// (m,l,O) share one reference max. Multi-chunk tiles write unnormalized
// partials to WS; attn_merge combines. Single-chunk tiles store O direct.
// Defer-rescale: skip oacc*=alpha when no lane's max grew (exact).
// Fallback: if ws too small, monolithic path (R8 behavior).
// MFMA layouts (HW-verified m89/m91/m118-m122), 16x16x32_bf16:
//   A[m=lane&15][k=quad*8+j], B[k=quad*8+j][n=lane&15],
//   C/D: row m = quad*4+reg, col n = lane&15.

#define T_TOK 4096
#define NH    16
#define NG    4
#define HD    128
#define NCU   9
#define NTILE 128

// Workspace layout (floats):
//   O_part[tile(128)][g(4)][chunk(4)][hw(4)][q(32)][d(128)] = 33,554,432 f
//   ml    [tile][g][chunk][hw][q][{m,l}]                    =    524,288 f
//   queue (ints): [0]=total, [1]=pop counter, [2..2049]=entries
#define ML_OFF 33554432l
#define Q_OFF  (ML_OFF + 524288l)

typedef short          short8_t __attribute__((ext_vector_type(8)));
typedef float          float4_t __attribute__((ext_vector_type(4)));
typedef unsigned int   uint2_t  __attribute__((ext_vector_type(2)));
typedef unsigned short ushort;

static __device__ inline unsigned pack2(float a, float b) {
    __hip_bfloat162 h = __float22bfloat162_rn(make_float2(a, b));
    union { __hip_bfloat162 h; unsigned u; } c; c.h = h;
    return c.u;
}
static __device__ inline short8_t cvt8(float4_t lo, float4_t hi) {
    union { unsigned u[4]; short8_t s; } r;
    r.u[0] = pack2(lo[0], lo[1]); r.u[1] = pack2(lo[2], lo[3]);
    r.u[2] = pack2(hi[0], hi[1]); r.u[3] = pack2(hi[2], hi[3]);
    return r.s;
}

// ---- the R10-verified tile body (unchanged math), parameterized ----
template <bool CHUNKED>
static __device__ __forceinline__ void attn_tile_body(
    const float* __restrict__ Q, const float* __restrict__ K,
    const float* __restrict__ V, const int* __restrict__ cu,
    float* __restrict__ O, float* __restrict__ WS,
    unsigned char* smem, int qtile, int g, int cz)
{
    ushort (*Ks)[32][136]   = (ushort (*)[32][136])smem;
    ushort (*Vt)[128][40]   = (ushort (*)[128][40])(smem + 17408);
    ushort (*pb)[2][16][40] = (ushort (*)[2][16][40])(smem + 37888);

    const int tid   = threadIdx.x;
    const int wave  = tid >> 6;          // 0..7
    const int split = wave >> 2;         // 0..1 (key-range half)
    const int hw    = wave & 3;
    const int lane  = tid & 63;
    const int h     = g * 4 + hw;        // query head; h//4 == g (jnp.repeat)
    const int col   = lane & 15;
    const int quad  = lane >> 4;

    const int qbase = qtile * 32;        // 32 q rows per block
    const int qq[2] = { qbase + col, qbase + 16 + col };

    // segment starts: per-lane per-tile, and block-uniform for k0
    int seg_start[2] = {0, 0}, seg0 = 0;
    #pragma unroll
    for (int j = 1; j < NCU; ++j) {
        int cj = cu[j];
        if (cj <= qq[0])  seg_start[0] = cj;
        if (cj <= qq[1])  seg_start[1] = cj;
        if (cj <= qbase)  seg0         = cj;
    }
    const int k0       = seg0 & ~31;
    const int nblk_tot = (qbase + 32 - k0) >> 5;      // 32-key blocks in span
    const int nc       = CHUNKED ? ((nblk_tot + 31) >> 5) : 1;
    if (CHUNKED && cz >= nc) return;                  // guard (queue never emits)
    int nblk = nblk_tot - (cz << 5);                  // k-blocks in this chunk
    if (CHUNKED && nblk > 32) nblk = 32;              // non-last chunks: even
    const int nb0    = (nblk + 1) >> 1;               // iterations per split
    const int kstart = k0 + (cz << 10) + split * nb0 * 32;

    // Q fragments (B-operand of S^T = K*Q^T), 2 tiles. dim = c*32+quad*8+j.
    short8_t qf[2][4];
    #pragma unroll
    for (int tt = 0; tt < 2; ++tt) {
        const float* qp = Q + ((long)qq[tt] * NH + h) * HD + quad * 8;
        #pragma unroll
        for (int c = 0; c < 4; ++c)
            qf[tt][c] = cvt8(*(const float4_t*)(qp + c * 32),
                             *(const float4_t*)(qp + c * 32 + 4));
    }

    float4_t oacc[2][8];
    #pragma unroll
    for (int tt = 0; tt < 2; ++tt)
        #pragma unroll
        for (int dt = 0; dt < 8; ++dt) oacc[tt][dt] = (float4_t){0.f, 0.f, 0.f, 0.f};

    float m_run[2] = {-10000.0f, -10000.0f};
    float l_run[2] = {0.0f, 0.0f};
    const float c_scale = 0.08838834764831845f * 1.4426950408889634f; // SCALE*log2e

    // staging thread mapping (256 threads per split, 32 keys x 128 dims)
    const int stid = tid & 255;
    const int ki  = stid >> 3;           // K: key-in-tile
    const int ch  = (stid & 7) * 16;     // K: dim chunk
    const int kp2 = (stid & 15) * 2;     // V: key pair
    const int dc  = (stid >> 4) * 8;     // V: dim chunk

    float4_t kreg[4], vreg[4];
    {
        int key = kstart + ki; if (key > T_TOK - 1) key = T_TOK - 1;
        const float* kp = K + ((long)key * NG + g) * HD + ch;
        kreg[0] = *(const float4_t*)kp;       kreg[1] = *(const float4_t*)(kp + 4);
        kreg[2] = *(const float4_t*)(kp + 8); kreg[3] = *(const float4_t*)(kp + 12);
        int key0 = kstart + kp2;     if (key0 > T_TOK - 1) key0 = T_TOK - 1;
        int key1 = kstart + kp2 + 1; if (key1 > T_TOK - 1) key1 = T_TOK - 1;
        const float* v0 = V + ((long)key0 * NG + g) * HD + dc;
        const float* v1 = V + ((long)key1 * NG + g) * HD + dc;
        vreg[0] = *(const float4_t*)v0; vreg[1] = *(const float4_t*)(v0 + 4);
        vreg[2] = *(const float4_t*)v1; vreg[3] = *(const float4_t*)(v1 + 4);
    }

    for (int it = 0; it < nb0; ++it) {
        const int kb = kstart + it * 32;
        __syncthreads();   // previous iter's LDS reads complete

        // ---- write prefetched K/V regs -> LDS (bf16), own split's buffers ----
        *(short8_t*)&Ks[split][ki][ch]     = cvt8(kreg[0], kreg[1]);
        *(short8_t*)&Ks[split][ki][ch + 8] = cvt8(kreg[2], kreg[3]);
        #pragma unroll
        for (int d = 0; d < 4; ++d) {
            *(unsigned*)&Vt[split][dc + d][kp2]     = pack2(vreg[0][d], vreg[2][d]);
            *(unsigned*)&Vt[split][dc + 4 + d][kp2] = pack2(vreg[1][d], vreg[3][d]);
        }
        __syncthreads();

        // ---- prefetch next 32-key block (in flight during compute) ----
        {
            int nb = kb + 32;
            int key = nb + ki; if (key > T_TOK - 1) key = T_TOK - 1;
            const float* kp = K + ((long)key * NG + g) * HD + ch;
            kreg[0] = *(const float4_t*)kp;       kreg[1] = *(const float4_t*)(kp + 4);
            kreg[2] = *(const float4_t*)(kp + 8); kreg[3] = *(const float4_t*)(kp + 12);
            int key0 = nb + kp2;     if (key0 > T_TOK - 1) key0 = T_TOK - 1;
            int key1 = nb + kp2 + 1; if (key1 > T_TOK - 1) key1 = T_TOK - 1;
            const float* v0 = V + ((long)key0 * NG + g) * HD + dc;
            const float* v1 = V + ((long)key1 * NG + g) * HD + dc;
            vreg[0] = *(const float4_t*)v0; vreg[1] = *(const float4_t*)(v0 + 4);
            vreg[2] = *(const float4_t*)v1; vreg[3] = *(const float4_t*)(v1 + 4);
        }

        // ---- S^T tiles: 8 K-frag reads feed 16 MFMAs (2 q-tiles) ----
        float4_t st[2][2];
        #pragma unroll
        for (int tt = 0; tt < 2; ++tt)
            #pragma unroll
            for (int t = 0; t < 2; ++t) st[tt][t] = (float4_t){0.f, 0.f, 0.f, 0.f};
        #pragma unroll
        for (int c = 0; c < 4; ++c) {
            short8_t kf0 = *(const short8_t*)&Ks[split][col][c * 32 + quad * 8];
            short8_t kf1 = *(const short8_t*)&Ks[split][16 + col][c * 32 + quad * 8];
            st[0][0] = __builtin_amdgcn_mfma_f32_16x16x32_bf16(kf0, qf[0][c], st[0][0], 0, 0, 0);
            st[0][1] = __builtin_amdgcn_mfma_f32_16x16x32_bf16(kf1, qf[0][c], st[0][1], 0, 0, 0);
            st[1][0] = __builtin_amdgcn_mfma_f32_16x16x32_bf16(kf0, qf[1][c], st[1][0], 0, 0, 0);
            st[1][1] = __builtin_amdgcn_mfma_f32_16x16x32_bf16(kf1, qf[1][c], st[1][1], 0, 0, 0);
        }

        // ---- mask + online softmax per q-tile (log2 domain) ----
        #pragma unroll
        for (int tt = 0; tt < 2; ++tt) {
            float tv[8];
            #pragma unroll
            for (int t = 0; t < 2; ++t)
                #pragma unroll
                for (int r = 0; r < 4; ++r) {
                    int key = kb + 16 * t + quad * 4 + r;
                    bool valid = (key <= qq[tt]) && (key >= seg_start[tt]);
                    tv[t * 4 + r] = valid ? st[tt][t][r] * c_scale : -30000.0f;
                }
            float tmax = tv[0];
            #pragma unroll
            for (int i = 1; i < 8; ++i) tmax = fmaxf(tmax, tv[i]);
            tmax = fmaxf(tmax, __shfl_xor(tmax, 16));
            tmax = fmaxf(tmax, __shfl_xor(tmax, 32));
            const float m_new = fmaxf(m_run[tt], tmax);
            float p[8], ps = 0.f;
            #pragma unroll
            for (int i = 0; i < 8; ++i) { p[i] = __builtin_exp2f(tv[i] - m_new); ps += p[i]; }
            ps += __shfl_xor(ps, 16);
            ps += __shfl_xor(ps, 32);
            // defer-rescale: when no lane's max grew, alpha==1 exactly ->
            // skip the O rescale pass and m/l update (wave-uniform branch).
            if (__any(tmax > m_run[tt])) {
                const float alpha = __builtin_exp2f(m_run[tt] - m_new);
                l_run[tt] = l_run[tt] * alpha + ps;
                m_run[tt] = m_new;
                #pragma unroll
                for (int dt = 0; dt < 8; ++dt) oacc[tt][dt] *= alpha;
            } else {
                l_run[tt] += ps;
            }

            uint2_t w0; w0.x = pack2(p[0], p[1]); w0.y = pack2(p[2], p[3]);
            uint2_t w1; w1.x = pack2(p[4], p[5]); w1.y = pack2(p[6], p[7]);
            *(uint2_t*)&pb[wave][tt][col][quad * 4]      = w0;
            *(uint2_t*)&pb[wave][tt][col][16 + quad * 4] = w1;
        }
        short8_t pf0 = *(const short8_t*)&pb[wave][0][col][quad * 8];
        short8_t pf1 = *(const short8_t*)&pb[wave][1][col][quad * 8];

        // ---- O^T += V^T * P^T : 8 V-frag reads feed 16 MFMAs ----
        #pragma unroll
        for (int dt = 0; dt < 8; ++dt) {
            short8_t vf = *(const short8_t*)&Vt[split][dt * 16 + col][quad * 8];
            oacc[0][dt] = __builtin_amdgcn_mfma_f32_16x16x32_bf16(vf, pf0, oacc[0][dt], 0, 0, 0);
            oacc[1][dt] = __builtin_amdgcn_mfma_f32_16x16x32_bf16(vf, pf1, oacc[1][dt], 0, 0, 0);
        }
    }

    // ---- merge split1's (m,l,O) into split0 via LDS (region reuse) ----
    float* Ob = (float*)smem;                  // [4 heads][16 q][132] floats
    float* cm = (float*)(smem + 34816);        // 64 floats per pass
    float* cl = (float*)(smem + 35840);
    #pragma unroll
    for (int tt = 0; tt < 2; ++tt) {
        __syncthreads();
        if (split == 1) {
            if (quad == 0) { cm[hw * 16 + col] = m_run[tt]; cl[hw * 16 + col] = l_run[tt]; }
            float* ob = Ob + (hw * 16 + col) * 132;
            #pragma unroll
            for (int dt = 0; dt < 8; ++dt)
                *(float4_t*)(ob + dt * 16 + quad * 4) = oacc[tt][dt];
        }
        __syncthreads();
        if (split == 0) {
            const float m1 = cm[hw * 16 + col], l1 = cl[hw * 16 + col];
            const float m  = fmaxf(m_run[tt], m1);
            const float a0 = __builtin_exp2f(m_run[tt] - m);
            const float a1 = __builtin_exp2f(m1 - m);
            const float* ob = Ob + (hw * 16 + col) * 132;
            #pragma unroll
            for (int dt = 0; dt < 8; ++dt) {
                float4_t o1 = *(const float4_t*)(ob + dt * 16 + quad * 4);
                oacc[tt][dt] = oacc[tt][dt] * a0 + o1 * a1;
            }
            l_run[tt] = l_run[tt] * a0 + l1 * a1;
            m_run[tt] = m;   // commit merged max: partial path stores (m,l,O)
                             // and all three must share one reference max
        }
    }

    // ---- epilogue (split 0 only) ----
    if (split == 0) {
        if (!CHUNKED || nc == 1) {
            // whole span in this item: normalized direct store
            #pragma unroll
            for (int tt = 0; tt < 2; ++tt) {
                const float inv_l = 1.0f / l_run[tt];
                float* op = O + ((long)qq[tt] * NH + h) * HD + quad * 4;
                #pragma unroll
                for (int dt = 0; dt < 8; ++dt) {
                    float4_t ov;
                    #pragma unroll
                    for (int r = 0; r < 4; ++r) ov[r] = oacc[tt][dt][r] * inv_l;
                    *(float4_t*)(op + dt * 16) = ov;
                }
            }
        } else {
            // multi-chunk: write unnormalized partial (m,l,O) to workspace
            const long slot = ((long)(qtile * 4 + g)) * 4 + cz;
            #pragma unroll
            for (int tt = 0; tt < 2; ++tt) {
                const int ql = tt * 16 + col;
                if (quad == 0) {
                    float* mlp = WS + ML_OFF + (slot * 128 + hw * 32 + ql) * 2;
                    mlp[0] = m_run[tt];
                    mlp[1] = l_run[tt];
                }
                float* op = WS + (slot * 128 + hw * 32 + ql) * 128 + quad * 4;
                #pragma unroll
                for (int dt = 0; dt < 8; ++dt)
                    *(float4_t*)(op + dt * 16) = oacc[tt][dt];
            }
        }
    }
}

// ---- build compacted live-work queue, heaviest tiles first ----
// qwork[0]=total entries, qwork[1]=pop counter (reset), qwork[2..]=entries
// entry = (tile<<4)|(g<<2)|cz, only cz<nc emitted. Runs every launch.
__global__ __launch_bounds__(128) void build_queue(
    const int* __restrict__ cu, int* __restrict__ qwork)
{
    __shared__ int nblk_s[NTILE];
    __shared__ int sortedE[NTILE + 1];
    const int t = threadIdx.x;           // tile id, 0..127

    const int qbase = t * 32;
    int seg0 = 0;
    #pragma unroll
    for (int j = 1; j < NCU; ++j) { int cj = cu[j]; if (cj <= qbase) seg0 = cj; }
    const int k0   = seg0 & ~31;
    const int nblk = (qbase + 32 - k0) >> 5;   // 1..128
    nblk_s[t] = nblk;
    __syncthreads();

    // rank by (nblk desc, tile asc) -- strict total order, unique ranks
    int r = 0;
    for (int j = 0; j < NTILE; ++j) {
        int nj = nblk_s[j];
        if (nj > nblk || (nj == nblk && j < t)) ++r;
    }
    const int nc = (nblk + 31) >> 5;           // 1..4
    sortedE[r] = 4 * nc;                       // entries this tile emits
    __syncthreads();
    if (t == 0) {                              // exclusive prefix (128 adds)
        int s = 0;
        for (int j = 0; j < NTILE; ++j) { int v = sortedE[j]; sortedE[j] = s; s += v; }
        sortedE[NTILE] = s;
        qwork[0] = s;                          // total
        qwork[1] = 0;                          // pop counter reset
    }
    __syncthreads();
    int off = 2 + sortedE[r];
    for (int g = 0; g < NG; ++g)
        for (int cz = 0; cz < nc; ++cz)
            qwork[off++] = (t << 4) | (g << 2) | cz;
}

// ---- persistent kernel: 512 resident blocks pop live items ----
__global__ __launch_bounds__(512) void attn_fwd_persist(
    const float* __restrict__ Q,
    const float* __restrict__ K,
    const float* __restrict__ V,
    const int*   __restrict__ cu,
    float*       __restrict__ O,
    float*       __restrict__ WS)
{
    __shared__ __align__(16) unsigned char smem[58368];
    __shared__ int pop_s;
    int* qwork = (int*)(WS + Q_OFF);
    const int qtotal = qwork[0];

    for (;;) {
        __syncthreads();                       // prior item's smem use done
        if (threadIdx.x == 0) pop_s = atomicAdd(&qwork[1], 1);
        __syncthreads();
        const int idx = pop_s;                 // block-uniform
        if (idx >= qtotal) return;
        const int ent = qwork[2 + idx];
        attn_tile_body<true>(Q, K, V, cu, O, WS, smem,
                             ent >> 4, (ent >> 2) & 3, ent & 3);
    }
}

// ---- monolithic fallback (R8 behavior, no workspace dependence) ----
__global__ __launch_bounds__(512) void attn_fwd_mono(
    const float* __restrict__ Q,
    const float* __restrict__ K,
    const float* __restrict__ V,
    const int*   __restrict__ cu,
    float*       __restrict__ O)
{
    __shared__ __align__(16) unsigned char smem[58368];
    attn_tile_body<false>(Q, K, V, cu, O, nullptr, smem,
                          (int)gridDim.x - 1 - (int)blockIdx.x,
                          (int)blockIdx.y, 0);
}

// Combine up to 4 chunk partials per (tile, g). Online merge, f32, log2
// domain. Only runs for multi-chunk tiles (the partial kernel already
// wrote O directly for nc==1).
__global__ __launch_bounds__(256) void attn_merge(
    const int*   __restrict__ cu,
    const float* __restrict__ WS,
    float*       __restrict__ O)
{
    const int tile  = blockIdx.x;
    const int g     = blockIdx.y;
    const int qbase = tile * 32;
    int seg0 = 0;
    #pragma unroll
    for (int j = 1; j < NCU; ++j) { int cj = cu[j]; if (cj <= qbase) seg0 = cj; }
    const int k0       = seg0 & ~31;
    const int nblk_tot = (qbase + 32 - k0) >> 5;
    const int nc       = (nblk_tot + 31) >> 5;
    if (nc <= 1) return;

    const int tid  = threadIdx.x;
    const int pair = tid >> 1;           // hw*32 + q  (128 pairs)
    const int half = tid & 1;            // which 64-float half of D
    const int hw   = pair >> 5;
    const int q    = pair & 31;

    float m = -30000.0f, l = 0.0f;
    float4_t acc[16];
    #pragma unroll
    for (int i = 0; i < 16; ++i) acc[i] = (float4_t){0.f, 0.f, 0.f, 0.f};

    for (int c = 0; c < nc; ++c) {
        const long slot = ((long)(tile * 4 + g)) * 4 + c;
        const float* mlp = WS + ML_OFF + (slot * 128 + pair) * 2;
        const float mc = mlp[0], lc = mlp[1];
        const float mn = fmaxf(m, mc);
        const float a0 = __builtin_exp2f(m - mn);
        const float a1 = __builtin_exp2f(mc - mn);
        l = l * a0 + lc * a1;
        const float* op = WS + (slot * 128 + pair) * 128 + half * 64;
        #pragma unroll
        for (int i = 0; i < 16; ++i) {
            float4_t v = *(const float4_t*)(op + i * 4);
            acc[i] = acc[i] * a0 + v * a1;
        }
        m = mn;
    }
    const float inv = 1.0f / l;
    float* o = O + ((long)(qbase + q) * NH + g * 4 + hw) * HD + half * 64;
    #pragma unroll
    for (int i = 0; i < 16; ++i)
        *(float4_t*)(o + i * 4) = acc[i] * inv;
}

extern "C" void kernel_launch(void* const* d_in, const int* in_sizes, int n_in,
                              void* d_out, int out_size, void* d_ws, size_t ws_size,
                              hipStream_t stream) {
    const float* Q  = (const float*)d_in[0];
    const float* K  = (const float*)d_in[1];
    const float* V  = (const float*)d_in[2];
    const int*   cu = (const int*)d_in[3];
    float*       O  = (float*)d_out;
    // floats: partials + ml + queue (2 header + 2048 entries as ints)
    const size_t need = (size_t)(33554432l + 524288l + 2056l) * sizeof(float);
    if (d_ws != nullptr && ws_size >= need) {
        float* WS = (float*)d_ws;
        build_queue<<<1, 128, 0, stream>>>(cu, (int*)(WS + Q_OFF));
        attn_fwd_persist<<<512, 512, 0, stream>>>(Q, K, V, cu, O, WS);
        attn_merge<<<dim3(T_TOK / 32, NG), 256, 0, stream>>>(
            cu, (const float*)WS, O);
    } else {
        // workspace too small: proven monolithic path (R8 behavior)
        attn_fwd_mono<<<dim3(T_TOK / 32, NG), 512, 0, stream>>>(Q, K, V, cu, O);
    }
}